// Round 9
// baseline (1747.725 us; speedup 1.0000x reference)
//
#include <hip/hip_runtime.h>
#include <stdint.h>

// ---------------- problem constants ----------------
#define EMBD   256
#define HID    512
#define KTOT   768            // EMB + HID
#define NCLS   50257
#define STEPS  512

// ---------------- persistent-kernel partition ----------------
#define NGROUP 8               // batch groups
#define GB     8               // batches per group
#define BPG    32              // blocks per group (hidden split)
#define HS     16              // hidden units per block -> 64 gate rows
#define UPITCH 776             // u row pitch in bf16 elems (768 + 8 pad)
#define RP     129             // red tile pitch in floats (129 mod 32 = 1 -> conflict-free)

typedef float f32x4  __attribute__((ext_vector_type(4)));
typedef short bf16x8 __attribute__((ext_vector_type(8)));
typedef unsigned long long u64;

__device__ __forceinline__ unsigned bf16_rne(float f) {
  unsigned u = __float_as_uint(f);
  return (u + 0x7FFFu + ((u >> 16) & 1u)) >> 16;
}
__device__ __forceinline__ float bf16_to_f32(unsigned b) {
  return __uint_as_float(b << 16);
}

// ============ kernel 1: embedding gather + bf16 hi/lo pack ============
__global__ void emb_prep(const int* __restrict__ x, const float* __restrict__ emb,
                         unsigned* __restrict__ emb_hl) {
  int base = blockIdx.x * 4;
  int k = threadIdx.x;
  for (int it = 0; it < 4; ++it) {
    int tok = base + it;
    int id = x[tok];
    float w = emb[(size_t)id * EMBD + k];
    unsigned hb = bf16_rne(w);
    unsigned lb = bf16_rne(w - bf16_to_f32(hb));
    emb_hl[(size_t)tok * EMBD + k] = hb | (lb << 16);
  }
}

// ============ kernel 2: persistent LSTM recurrence ============
// 256 blocks (cooperative), 512 thr. group g = blockIdx&7, slice s = blockIdx>>3.
// h exchange: SELF-SYNCHRONIZING u64 {tag=step+1 | hi|lo} words, relaxed
// agent-scope 8B atomics, parity double buffer. Tag match implies validity;
// a block stores step+1 only after consuming all of step, which proves every
// block finished reading step-1 -> overwriting step-1 slots is safe.
// R1: coalesced polls (lane l reads unit j*64+l).
// R8: emb register prefetch (no vmcnt wait before the poll).
// R9: DONE-WORD PRE-GATE. Model: spinning re-loads of the full 4KB h-slice
//   (64 lines/wave/round, ~1e5 line-requests/round grid-wide) sit in
//   equilibrium with LLC request bandwidth — RT inflates until request rate
//   matches service rate (explains R1's -36% from 4x fewer lines and R7's
//   RMW-storm regression). Fix without R7's flaws: writers publish
//   done[g][s]=step+1 via ONE PLAIN STORE (no RMW) after a trailing
//   __syncthreads whose compiler-emitted vmcnt(0) drain guarantees all 8
//   waves' h-stores are LLC-ack'd first (done => data visible, airtight).
//   Readers: ALL waves poll done[g][lane&31] directly (2 lines per group,
//   shared by its 256 waves; no relay hop), then run the UNCHANGED
//   tag-verified data round exactly once. Spin traffic: 64 lines/wave ->
//   2 shared lines/group. Data-tag check remains the only correctness guard.
__global__ __launch_bounds__(512, 2) void lstm_persist(
    const float* __restrict__ Ww, const float* __restrict__ Wb,
    const unsigned* __restrict__ emb_hl,
    u64* __restrict__ hbuf,
    unsigned* __restrict__ done,
    unsigned short* __restrict__ h_hi, unsigned short* __restrict__ h_lo)
{
  __shared__ __align__(16) unsigned short u_hi[16 * UPITCH];
  __shared__ __align__(16) unsigned short u_lo[16 * UPITCH];
  __shared__ __align__(16) float red[32 * RP];   // [wave*4+nt][lane<32][4] padded

  const int tid  = threadIdx.x;
  const int wave = tid >> 6;
  const int lane = tid & 63;
  const int g = blockIdx.x & 7;     // batch group 0..7  (XCD-local under rr)
  const int s = blockIdx.x >> 3;    // hidden slice 0..31

  // zero u rows once (rows 8..15 are M-padding and stay zero forever)
  for (int i = tid; i < 16 * UPITCH; i += 512) { u_hi[i] = 0; u_lo[i] = 0; }

  // ---- load W B-fragments into registers (one time) ----
  const int cn = lane & 15;
  const int qk = (lane >> 4) * 8;
  bf16x8 whi[3][4], wlo[3][4];
#pragma unroll
  for (int i = 0; i < 3; ++i) {
    int kt = wave * 3 + i;
    int k0 = kt * 32 + qk;
#pragma unroll
    for (int nt = 0; nt < 4; ++nt) {
      int row = nt * 512 + s * HS + cn;
      const float* src = Ww + (size_t)row * KTOT + k0;
      float4 w0 = *(const float4*)src;
      float4 w1 = *(const float4*)(src + 4);
      float wv[8] = {w0.x, w0.y, w0.z, w0.w, w1.x, w1.y, w1.z, w1.w};
#pragma unroll
      for (int j = 0; j < 8; ++j) {
        unsigned hb = bf16_rne(wv[j]);
        unsigned lb = bf16_rne(wv[j] - bf16_to_f32(hb));
        whi[i][nt][j] = (short)hb;
        wlo[i][nt][j] = (short)lb;
      }
    }
  }

  const float bias = Wb[(lane >> 4) * 512 + s * HS + (lane & 15)];

  float Cst = 0.0f;  // cell state for (batch=wave, unit=lane) on lanes<16

  const unsigned* embg = emb_hl + (size_t)(g * GB) * STEPS * EMBD;
  u64* hg = hbuf + (size_t)g * 2 * GB * HID;
  unsigned* dg = done + g * 32;

  // per-thread emb prefetch pointer: thread covers batch eb, cols ek0..ek0+3
  const int ef0 = tid * 4;
  const int eb  = ef0 >> 8, ek0 = ef0 & 255;
  const unsigned* embp = embg + (size_t)eb * STEPS * EMBD + ek0;

  // prologue: prefetch step 0 into registers
  uint4 embv = *(const uint4*)embp;

  __syncthreads();

  for (int step = 0; step < STEPS; ++step) {
    // ---- stage emb from REGISTERS (no memory wait before the gate) ----
    {
      unsigned h01 = (embv.x & 0xFFFFu) | ((embv.y & 0xFFFFu) << 16);
      unsigned h23 = (embv.z & 0xFFFFu) | ((embv.w & 0xFFFFu) << 16);
      unsigned l01 = (embv.x >> 16) | (embv.y & 0xFFFF0000u);
      unsigned l23 = (embv.z >> 16) | (embv.w & 0xFFFF0000u);
      *(uint2*)&u_hi[eb * UPITCH + ek0] = make_uint2(h01, h23);
      *(uint2*)&u_lo[eb * UPITCH + ek0] = make_uint2(l01, l23);
    }
    // ---- done-word pre-gate: 2 shared lines per group, all waves ----
    if (step > 0) {
      const unsigned want = (unsigned)step;
      while (__hip_atomic_load(&dg[lane & 31], __ATOMIC_RELAXED,
                               __HIP_MEMORY_SCOPE_AGENT) < want)
        __builtin_amdgcn_s_sleep(1);
    }
    // ---- tag-verified data round + stage h (passes first try after gate) ----
    {
      const u64* hp = hg + ((size_t)(step & 1) * GB + wave) * HID;
      u64 v[8];
      const unsigned want = (unsigned)step;
      while (true) {
        bool ok = true;
#pragma unroll
        for (int j = 0; j < 8; ++j)
          v[j] = __hip_atomic_load(&hp[j * 64 + lane], __ATOMIC_RELAXED,
                                   __HIP_MEMORY_SCOPE_AGENT);
#pragma unroll
        for (int j = 0; j < 8; ++j)
          ok &= ((unsigned)(v[j] >> 32) == want);
        if (ok) break;
        __builtin_amdgcn_s_sleep(1);
      }
#pragma unroll
      for (int j = 0; j < 8; ++j) {
        unsigned w32 = (unsigned)v[j];
        u_hi[wave * UPITCH + EMBD + j * 64 + lane] = (unsigned short)(w32 & 0xFFFFu);
        u_lo[wave * UPITCH + EMBD + j * 64 + lane] = (unsigned short)(w32 >> 16);
      }
    }
    // ---- issue next step's emb prefetch (latency hides under MFMA+reduce) ----
    {
      int nstep = (step + 1 < STEPS) ? step + 1 : step;
      embv = *(const uint4*)(embp + (size_t)nstep * EMBD);
    }
    __syncthreads();   // S1: u staged

    // ---- gates = u @ W_sliceT : MFMA, k-split 8 ways over waves ----
    f32x4 acc[4] = {{0.f,0.f,0.f,0.f},{0.f,0.f,0.f,0.f},
                    {0.f,0.f,0.f,0.f},{0.f,0.f,0.f,0.f}};
#pragma unroll
    for (int i = 0; i < 3; ++i) {
      int k0 = (wave * 3 + i) * 32 + qk;
      int m = lane & 15;
      bf16x8 ahi = *(const bf16x8*)&u_hi[m * UPITCH + k0];
      bf16x8 alo = *(const bf16x8*)&u_lo[m * UPITCH + k0];
#pragma unroll
      for (int nt = 0; nt < 4; ++nt) {
        acc[nt] = __builtin_amdgcn_mfma_f32_16x16x32_bf16(ahi, whi[i][nt], acc[nt], 0, 0, 0);
        acc[nt] = __builtin_amdgcn_mfma_f32_16x16x32_bf16(ahi, wlo[i][nt], acc[nt], 0, 0, 0);
        acc[nt] = __builtin_amdgcn_mfma_f32_16x16x32_bf16(alo, whi[i][nt], acc[nt], 0, 0, 0);
      }
    }
    // only lanes<32 hold valid rows (m=0..7); pitch 129 kills bank conflicts
    if (lane < 32) {
#pragma unroll
      for (int nt = 0; nt < 4; ++nt)
        *(f32x4*)&red[(wave * 4 + nt) * RP + lane * 4] = acc[nt];
    }
    __syncthreads();   // S2: red visible

    // ---- k-split reduction: thread owns (batch=wave, gate-row=lane) ----
    float gsum = bias;
    {
      int tq = lane >> 4;
      int rbase = ((((wave >> 2) << 4) | (lane & 15)) << 2) + (wave & 3);
#pragma unroll
      for (int w = 0; w < 8; ++w)
        gsum += red[(w * 4 + tq) * RP + rbase];
    }

    // ---- nonlinearities: lanes 0-15 f, 16-31 i, 32-47 o, 48-63 c~ ----
    float scl = (lane >= 48) ? 2.0f : 1.0f;
    float y = 1.0f / (1.0f + __expf(-gsum * scl));
    float act = (lane >= 48) ? (2.0f * y - 1.0f) : y;   // tanh via sigmoid
    float ig = __shfl(act, lane + 16);
    float og = __shfl(act, lane + 32);
    float cg_ = __shfl(act, lane + 48);
    if (lane < 16) {
      Cst = act * Cst + ig * cg_;
      float t2 = 1.0f / (1.0f + __expf(-2.0f * Cst));
      float hv = og * (2.0f * t2 - 1.0f);
      unsigned hb = bf16_rne(hv);
      unsigned lb = bf16_rne(hv - bf16_to_f32(hb));
      u64 pack = ((u64)(unsigned)(step + 1) << 32) | (u64)(hb | (lb << 16));
      __hip_atomic_store(
          &hg[((size_t)((step + 1) & 1) * GB + wave) * HID + s * HS + lane],
          pack, __ATOMIC_RELAXED, __HIP_MEMORY_SCOPE_AGENT);
      if (step == STEPS - 1) {
        int m = g * GB + wave, k = s * HS + lane;
        h_hi[m * HID + k] = (unsigned short)hb;
        h_lo[m * HID + k] = (unsigned short)lb;
      }
    }
    __syncthreads();   // S3: drains all waves' h-stores (vmcnt(0) before barrier)
    // done => all this block's tag=(step+1) words are LLC-visible
    if (tid == 0)
      __hip_atomic_store(&dg[s], (unsigned)(step + 1), __ATOMIC_RELAXED,
                         __HIP_MEMORY_SCOPE_AGENT);
  }
}

// ============ kernel 3: out = h_final @ fcT + bias (MFMA hi/lo) ============
__device__ __forceinline__ void cvt8(const float4& a, const float4& b,
                                     bf16x8& hi, bf16x8& lo) {
  float v[8] = {a.x, a.y, a.z, a.w, b.x, b.y, b.z, b.w};
#pragma unroll
  for (int j = 0; j < 8; ++j) {
    unsigned hb = bf16_rne(v[j]);
    hi[j] = (short)hb;
    lo[j] = (short)bf16_rne(v[j] - bf16_to_f32(hb));
  }
}

__global__ __launch_bounds__(512) void fc_mfma(
    const unsigned short* __restrict__ h_hi, const unsigned short* __restrict__ h_lo,
    const float* __restrict__ fcw, const float* __restrict__ fcb,
    float* __restrict__ out)
{
  const int tid = threadIdx.x, wave = tid >> 6, lane = tid & 63;
  const int cn = lane & 15;
  const int qk = (lane >> 4) * 8;
  const int cls  = blockIdx.x * 128 + wave * 16 + cn;
  const int clsc = cls < NCLS ? cls : NCLS - 1;

  f32x4 acc[4] = {{0.f,0.f,0.f,0.f},{0.f,0.f,0.f,0.f},
                  {0.f,0.f,0.f,0.f},{0.f,0.f,0.f,0.f}};
#pragma unroll 2
  for (int kt = 0; kt < 16; ++kt) {
    int k0 = kt * 32 + qk;
    const float* bp = fcw + (size_t)clsc * HID + k0;
    float4 b0 = *(const float4*)bp;
    float4 b1 = *(const float4*)(bp + 4);
    bf16x8 bhi, blo;
    cvt8(b0, b1, bhi, blo);
#pragma unroll
    for (int mt = 0; mt < 4; ++mt) {
      bf16x8 ahi = *(const bf16x8*)&h_hi[(size_t)(mt * 16 + cn) * HID + k0];
      bf16x8 alo = *(const bf16x8*)&h_lo[(size_t)(mt * 16 + cn) * HID + k0];
      acc[mt] = __builtin_amdgcn_mfma_f32_16x16x32_bf16(ahi, bhi, acc[mt], 0, 0, 0);
      acc[mt] = __builtin_amdgcn_mfma_f32_16x16x32_bf16(ahi, blo, acc[mt], 0, 0, 0);
      acc[mt] = __builtin_amdgcn_mfma_f32_16x16x32_bf16(alo, bhi, acc[mt], 0, 0, 0);
    }
  }
  if (cls < NCLS) {
    float bias = fcb[cls];
#pragma unroll
    for (int mt = 0; mt < 4; ++mt)
#pragma unroll
      for (int j = 0; j < 4; ++j) {
        int m = mt * 16 + (lane >> 4) * 4 + j;
        out[(size_t)m * NCLS + cls] = acc[mt][j] + bias;
      }
  }
}

// ============ launcher ============
extern "C" void kernel_launch(void* const* d_in, const int* in_sizes, int n_in,
                              void* d_out, int out_size, void* d_ws, size_t ws_size,
                              hipStream_t stream) {
  const int*   x   = (const int*)d_in[0];
  const float* emb = (const float*)d_in[1];
  const float* Ww  = (const float*)d_in[2];
  const float* Wb  = (const float*)d_in[3];
  const float* fcw = (const float*)d_in[4];
  const float* fcb = (const float*)d_in[5];
  float* out = (float*)d_out;

  // workspace carve-up
  char* ws = (char*)d_ws;
  u64*            hbuf   = (u64*)ws;                          // 524,288 B (8g x 2slot x 8b x 512 x 8B)
  unsigned*       done   = (unsigned*)(ws + 524288);          //   4,096 B (8g x 32 words used)
  unsigned short* h_hi   = (unsigned short*)(ws + 528384);    //  65,536 B
  unsigned short* h_lo   = (unsigned short*)(ws + 528384 + 65536);
  unsigned*       emb_hl = (unsigned*)(ws + 528384 + 131072); // 33.5 MB

  // zero h exchange buffer + done words:
  // tag=0 == "h for step 0 valid and zero"; done=0 == "tag-0 h available"
  hipMemsetAsync(hbuf, 0, 528384, stream);

  emb_prep<<<8192, 256, 0, stream>>>(x, emb, emb_hl);

  void* args[] = { (void*)&Ww, (void*)&Wb, (void*)&emb_hl,
                   (void*)&hbuf, (void*)&done, (void*)&h_hi, (void*)&h_lo };
  hipLaunchCooperativeKernel((void*)lstm_persist, dim3(256), dim3(512),
                             args, 0, stream);

  fc_mfma<<<(NCLS + 127) / 128, 512, 0, stream>>>(h_hi, h_lo, fcw, fcb, out);
}